// Round 9
// baseline (220.616 us; speedup 1.0000x reference)
//
#include <hip/hip_runtime.h>

typedef unsigned long long u64;
typedef unsigned int u32;

constexpr int D = 48, H = 384, W = 384;
constexpr int WPR = 6;                    // 384 bits / 64 per row (real words)
constexpr int PADW = 8;                   // padded words per row: [pad, w0..w5, pad]
constexpr int NVOX = D * H * W;           // 7,077,888
constexpr int NWVOL = D * H * WPR;        // 110,592 packed words per volume
constexpr int MPAD2 = 52;                 // padded change-mask array (u64s)
constexpr int NPZ = (H + 2) * PADW;       // padded words per z-slice = 3088
constexpr int MWZ = (NPZ + 63) >> 6;      // logical mask words for z = 49
constexpr int NXY = (D + 2) * PADW;       // padded words per xy slice = 400
constexpr int NTILE = D * 36;             // 1728 bit-transpose tiles (64x64)
constexpr size_t THIN_SMEM = (size_t)16 * 2 * NXY * 8;   // 102,400 B

// full adder: s = a+b+c (bit-sliced), cy = carry
__device__ __forceinline__ void fa(u64 a, u64 b, u64 c, u64& s, u64& cy) {
  u64 x = a ^ b;
  s = x ^ c;
  cy = (a & b) | (c & x);
}

// One Zhang-Suen subiteration for one packed word, all neighbors in registers.
__device__ __forceinline__ u64 zs_regs(u64 w00, u64 w01, u64 w02,
                                       u64 w10, u64 w11, u64 w12,
                                       u64 w20, u64 w21, u64 w22, bool first) {
  const u64 P2 = w01;                          // N
  const u64 P3 = (w01 >> 1) | (w02 << 63);     // NE
  const u64 P4 = (w11 >> 1) | (w12 << 63);     // E
  const u64 P5 = (w21 >> 1) | (w22 << 63);     // SE
  const u64 P6 = w21;                          // S
  const u64 P7 = (w21 << 1) | (w20 >> 63);     // SW
  const u64 P8 = (w11 << 1) | (w10 >> 63);     // W
  const u64 P9 = (w01 << 1) | (w00 >> 63);     // NW

  u64 s1, c1, s2, c2, s3, c3, u0, u1, v1, v2;
  fa(P2, P3, P4, s1, c1);
  fa(P5, P6, P7, s2, c2);
  fa(P8, P9, 0ull, s3, c3);
  fa(s1, s2, s3, u0, u1);
  fa(c1, c2, c3, v1, v2);
  u64 b1 = u1 ^ v1, k2 = u1 & v1;
  u64 b2 = v2 ^ k2, b3 = v2 & k2;
  u64 condB = (b1 | b2 | b3) & ~(b3 | (b2 & b1 & u0));   // 2<=B<=6

  u64 t0 = ~P2 & P3, t1 = ~P3 & P4, t2 = ~P4 & P5, t3 = ~P5 & P6;
  u64 t4 = ~P6 & P7, t5 = ~P7 & P8, t6 = ~P8 & P9, t7 = ~P9 & P2;
  fa(t0, t1, t2, s1, c1);
  fa(t3, t4, t5, s2, c2);
  fa(t6, t7, 0ull, s3, c3);
  fa(s1, s2, s3, u0, u1);
  fa(c1, c2, c3, v1, v2);
  u64 a1 = u1 ^ v1, j2 = u1 & v1;
  u64 a2 = v2 ^ j2, a3 = v2 & j2;
  u64 condA = u0 & ~(a1 | a2 | a3);                      // A == 1

  u64 cc = first ? ((~(P2 & P4 & P6)) & (~(P4 & P6 & P8)))
                 : ((~(P2 & P4 & P8)) & (~(P2 & P6 & P8)));
  return w11 & ~(condB & condA & cc);
}

// Test 3 bits (padded word indices q..q+2) of the padded change mask U.
__device__ __forceinline__ bool dirty3(const u64* U, int q) {
  const int pb = q + 64;
  const int w = pb >> 6, sh = pb & 63;
  u64 v = U[w] >> sh;
  if (sh > 61) v |= U[w + 1] << (64 - sh);
  return (v & 7ull) != 0;
}

// One pruned subiteration over a z-slice: group(64-word) pre-test, then exact
// word-level dirty3 test. Clean words are fully skipped (dst holds the value
// from two passes ago, which is provably still correct).
template<bool FIRST>
__device__ __forceinline__ void subpassZ(const u64* __restrict__ src, u64* __restrict__ dst,
                                         u64* rawW, const u64* rawPrev,
                                         u64* Uw, const u64* Ur,
                                         u32* gmW, const u32* gmR,
                                         int* chgflag, int tid, int nthr) {
  int anych = 0;
  for (int base = 0; base < NPZ; base += nthr) {
    const int idx = base + tid;
    int changed = 0;
    const bool valid = idx < NPZ;
    if (valid) {
      const int mw = 1 + (idx >> 6);
      if (gmR[mw - 1] | gmR[mw] | gmR[mw + 1]) {         // group-level pre-test
        const bool dirty = dirty3(Ur, idx - PADW - 1)
                         | dirty3(Ur, idx - 1)
                         | dirty3(Ur, idx + PADW - 1);
        if (dirty) {
          const u64 old = src[idx];
          u64 nw = 0;
          if (old) {
            nw = zs_regs(src[idx - PADW - 1], src[idx - PADW], src[idx - PADW + 1],
                         src[idx - 1], old, src[idx + 1],
                         src[idx + PADW - 1], src[idx + PADW], src[idx + PADW + 1], FIRST);
            changed = (nw != old);
          }
          dst[idx] = nw;
          anych |= changed;
        }
      }
    }
    const u64 bal = __ballot(changed != 0);
    if ((tid & 63) == 0 && valid) {
      const int mw = 1 + (idx >> 6);
      rawW[mw] = bal;
      const u64 uw = bal | rawPrev[mw];
      Uw[mw] = uw;
      gmW[mw] = (uw != 0ull) ? 1u : 0u;
    }
  }
  if (anych) *chgflag = 1;
}

// One xy subpass executed by a single wave with lockstep LDS semantics.
template<bool FIRST>
__device__ __forceinline__ void pass_xy(volatile u64* S, volatile u64* Dd,
                                        int lane, u64& anyc) {
  #pragma unroll
  for (int k = 0; k < 7; ++k) {
    const int idx = lane + (k << 6);
    if (idx >= NXY) break;
    const u64 old = S[idx];
    u64 nw = 0;
    if (old) {
      const u64 n00 = S[idx - 9], n01 = S[idx - 8], n02 = S[idx - 7];
      const u64 n10 = S[idx - 1],                   n12 = S[idx + 1];
      const u64 n20 = S[idx + 7], n21 = S[idx + 8], n22 = S[idx + 9];
      nw = zs_regs(n00, n01, n02, n10, old, n12, n20, n21, n22, FIRST);
    }
    Dd[idx] = nw;
    anyc |= (old ^ nw);
  }
}

// 96 blocks: b<48 -> one z-slice (barrier loop, pruned);
//            b>=48 -> 16 waves, each thinning one xy slice barrier-free.
__global__ __launch_bounds__(1024) void thin_all(const u64* __restrict__ maskP,
                                                 const u64* __restrict__ maskX,
                                                 u64* __restrict__ skelZY,
                                                 u64* __restrict__ skelX) {
  extern __shared__ u64 smem[];
  __shared__ int s_chg[2];
  const int b = blockIdx.x;
  const int tid = threadIdx.x;

  if (b < D) {
    // ---------------- z-slice path ----------------
    u64* A = smem;
    u64* B = A + NPZ;
    u64* raw0 = B + NPZ;
    u64* raw1 = raw0 + MPAD2;
    u64* Um0 = raw1 + MPAD2;
    u64* Um1 = Um0 + MPAD2;
    u32* gm0 = (u32*)(Um1 + MPAD2);
    u32* gm1 = gm0 + MPAD2;

    for (int idx = tid; idx < NPZ; idx += 1024) {
      const int rp = idx >> 3, cp = idx & 7;
      u64 v = 0;
      if (rp >= 1 && rp <= H && cp >= 1 && cp <= WPR)
        v = maskP[(b * H + (rp - 1)) * WPR + (cp - 1)];
      A[idx] = v;
      B[idx] = 0;
    }
    for (int t = tid; t < 4 * MPAD2; t += 1024) {
      const int arr = t / MPAD2, j = t - arr * MPAD2;
      const u64 v = ((arr & 1) && j >= 1 && j <= MWZ) ? ~0ull : 0ull;
      if (arr == 0) raw0[j] = v;
      else if (arr == 1) raw1[j] = v;
      else if (arr == 2) Um0[j] = v;
      else Um1[j] = v;
    }
    for (int t = tid; t < 2 * MPAD2; t += 1024) {
      const int arr = t / MPAD2, j = t - arr * MPAD2;
      const u32 v = (arr == 1 && j >= 1 && j <= MWZ) ? 1u : 0u;
      if (arr == 0) gm0[j] = v; else gm1[j] = v;
    }
    if (tid < 2) s_chg[tid] = 0;
    __syncthreads();

    int k = 0;
    while (true) {
      subpassZ<true >(A, B, raw0, raw1, Um0, Um1, gm0, gm1, &s_chg[k], tid, 1024);
      __syncthreads();
      if (tid == 0) s_chg[k ^ 1] = 0;
      subpassZ<false>(B, A, raw1, raw0, Um1, Um0, gm1, gm0, &s_chg[k], tid, 1024);
      __syncthreads();
      if (s_chg[k] == 0) break;
      k ^= 1;
    }

    for (int idx = tid; idx < NPZ; idx += 1024) {
      const int rp = idx >> 3, cp = idx & 7;
      if (rp < 1 || rp > H || cp < 1 || cp > WPR) continue;
      const u64 w = A[idx];
      if (!w) continue;
      atomicOr(&skelZY[(b * H + (rp - 1)) * WPR + (cp - 1)], w);
    }
  } else {
    // ---------------- xy wave path (no block barriers) ----------------
    const int wave = tid >> 6, lane = tid & 63;
    const int s = (b - D) * 16 + wave;           // 0..383 x-slices, 384..767 y-slices
    volatile u64* A = smem + wave * (2 * NXY);
    volatile u64* Bv = A + NXY;

    for (int idx = lane; idx < NXY; idx += 64) {
      const int rp = idx >> 3, cp = idx & 7;
      u64 v = 0;
      if (rp >= 1 && rp <= D && cp >= 1 && cp <= WPR) {
        if (s < W) v = maskX[((rp - 1) * W + s) * WPR + (cp - 1)];
        else       v = maskP[((rp - 1) * H + (s - W)) * WPR + (cp - 1)];
      }
      A[idx] = v;
      Bv[idx] = 0;
    }
    __builtin_amdgcn_wave_barrier();

    while (true) {
      u64 anyc = 0;
      pass_xy<true >(A, Bv, lane, anyc);
      __builtin_amdgcn_wave_barrier();
      pass_xy<false>(Bv, A, lane, anyc);
      __builtin_amdgcn_wave_barrier();
      if (__ballot(anyc != 0) == 0) break;
    }

    for (int idx = lane; idx < NXY; idx += 64) {
      const int rp = idx >> 3, cp = idx & 7;
      if (rp < 1 || rp > D || cp < 1 || cp > WPR) continue;
      const u64 w = A[idx];
      if (s < W) {
        skelX[((rp - 1) * W + s) * WPR + (cp - 1)] = w;   // exclusive full coverage
      } else if (w) {
        atomicOr(&skelZY[((rp - 1) * H + (s - W)) * WPR + (cp - 1)], w);
      }
    }
  }
}

// Pack mask bits (v==1.0f) along x; zero the skelZY accumulator.
__global__ void init_pack(const float* __restrict__ in, u64* __restrict__ maskP,
                          u64* __restrict__ skelZY) {
  const int lane = threadIdx.x & 63;
  const int gwave = (blockIdx.x * blockDim.x + threadIdx.x) >> 6;
  const int nwaves = (gridDim.x * blockDim.x) >> 6;
  for (int widx = gwave; widx < NWVOL; widx += nwaves) {
    float v = in[(size_t)widx * 64 + lane];
    u64 w = __ballot(v == 1.0f);
    if (lane == 0) {
      maskP[widx] = w;
      skelZY[widx] = 0;
    }
  }
}

// Bit-transpose maskP (packed x) -> maskX ([z][x][yw], packed y). One wave per
// 64x64 bit tile; 1728 tiles total, fully written (no init needed).
__global__ void transpose_in(const u64* __restrict__ maskP, u64* __restrict__ maskX) {
  const int gw = (blockIdx.x * blockDim.x + threadIdx.x) >> 6;
  const int lane = threadIdx.x & 63;
  const int z = gw / 36, rem = gw - z * 36;
  const int yw = rem / 6, xw = rem - yw * 6;
  const u64 wp = maskP[(z * H + yw * 64 + lane) * WPR + xw];   // bits indexed by x
  u64 mine = 0;
  #pragma unroll 8
  for (int i = 0; i < 64; ++i) {
    u64 wi = __ballot((wp >> i) & 1ull);     // bit l = pixel(y=yw*64+l, x=xw*64+i)
    if (lane == i) mine = wi;
  }
  maskX[(z * W + xw * 64 + lane) * WPR + yw] = mine;
}

// Transpose skelX ([z][x][yw], packed y) into packed-x layout, OR into skelZY.
__global__ void transpose_or(const u64* __restrict__ skelX,
                             u64* __restrict__ skelZY) {
  const int gw = (blockIdx.x * blockDim.x + threadIdx.x) >> 6;
  const int lane = threadIdx.x & 63;
  const int z = gw / 36, rem = gw - z * 36;
  const int yw = rem / 6, xw = rem - yw * 6;
  const int x = xw * 64 + lane;
  const u64 wx = skelX[(z * W + x) * WPR + yw];   // bits indexed by y
  u64 mine = 0;
  #pragma unroll 8
  for (int j = 0; j < 64; ++j) {
    u64 wj = __ballot((wx >> j) & 1ull);
    if (lane == j) mine = wj;
  }
  const int y = yw * 64 + lane;
  if (mine) skelZY[(z * H + y) * WPR + xw] |= mine;   // exclusive owner post-thin
}

// 6-connected dilation per word (computed once into LDS) + mask + coalesced
// float4 expansion. One block = 64 words = 4096 voxels.
__global__ __launch_bounds__(256) void dilate_expand(const u64* __restrict__ maskP,
                                                     const u64* __restrict__ skelZY,
                                                     float* __restrict__ out) {
  __shared__ u64 rw[64];
  const int tid = threadIdx.x;
  const int wbase = blockIdx.x * 64;
  if (tid < 64) {
    const int wi = wbase + tid;
    const int wc = wi % WPR;
    const int row = wi / WPR;        // row = z*H + y
    const int y = row % H;
    const int z = row / H;
    const u64 S = skelZY[wi];
    const u64 L = (wc > 0) ? skelZY[wi - 1] : 0ull;
    const u64 Rw = (wc < WPR - 1) ? skelZY[wi + 1] : 0ull;
    u64 d = S | (S << 1) | (L >> 63) | (S >> 1) | (Rw << 63);
    if (y > 0)     d |= skelZY[wi - WPR];
    if (y < H - 1) d |= skelZY[wi + WPR];
    if (z > 0)     d |= skelZY[wi - H * WPR];
    if (z < D - 1) d |= skelZY[wi + H * WPR];
    rw[tid] = d & maskP[wi];
  }
  __syncthreads();
  float4* o4 = reinterpret_cast<float4*>(out + (size_t)wbase * 64);
  #pragma unroll
  for (int k = 0; k < 4; ++k) {
    const int f = tid + 256 * k;
    const u64 bits = rw[f >> 4] >> ((f & 15) * 4);
    float4 o;
    o.x = (float)(bits & 1ull);
    o.y = (float)((bits >> 1) & 1ull);
    o.z = (float)((bits >> 2) & 1ull);
    o.w = (float)((bits >> 3) & 1ull);
    o4[f] = o;
  }
}

extern "C" void kernel_launch(void* const* d_in, const int* in_sizes, int n_in,
                              void* d_out, int out_size, void* d_ws, size_t ws_size,
                              hipStream_t stream) {
  const float* in = (const float*)d_in[0];
  float* out = (float*)d_out;
  u64* wsw = (u64*)d_ws;                 // need 4 * 110592 * 8 B = 3.54 MB
  u64* maskP = wsw;
  u64* skelZY = wsw + NWVOL;
  u64* skelX = wsw + 2 * NWVOL;
  u64* maskX = wsw + 3 * NWVOL;

  (void)hipFuncSetAttribute((const void*)thin_all,
                            hipFuncAttributeMaxDynamicSharedMemorySize,
                            (int)THIN_SMEM);

  init_pack<<<1728, 256, 0, stream>>>(in, maskP, skelZY);
  transpose_in<<<(NTILE * 64) / 256, 256, 0, stream>>>(maskP, maskX);
  thin_all<<<D + 768 / 16, 1024, THIN_SMEM, stream>>>(maskP, maskX, skelZY, skelX);
  transpose_or<<<(NWVOL + 255) / 256, 256, 0, stream>>>(skelX, skelZY);
  dilate_expand<<<NWVOL / 64, 256, 0, stream>>>(maskP, skelZY, out);
}

// Round 10
// 88.995 us; speedup vs baseline: 2.4790x; 2.4790x over previous
//
#include <hip/hip_runtime.h>

typedef unsigned long long u64;
typedef unsigned int u32;

constexpr int D = 48, H = 384, W = 384;
constexpr int WPR = 6;                    // 384 bits / 64 per row (real words)
constexpr int PADW = 8;                   // padded words per row: [pad, w0..w5, pad]
constexpr int NVOX = D * H * W;           // 7,077,888
constexpr int NWVOL = D * H * WPR;        // 110,592 packed words per volume
constexpr int MPAD2 = 52;                 // padded change-mask array (u64s)
constexpr int NPZ = (H + 2) * PADW;       // padded words per z-slice = 3088
constexpr int MWZ = (NPZ + 63) >> 6;      // logical mask words for z = 49
constexpr int NXY = (D + 2) * PADW;       // padded words per xy slice = 400

// full adder: s = a+b+c (bit-sliced), cy = carry
__device__ __forceinline__ void fa(u64 a, u64 b, u64 c, u64& s, u64& cy) {
  u64 x = a ^ b;
  s = x ^ c;
  cy = (a & b) | (c & x);
}

// One Zhang-Suen subiteration for one packed word, all neighbors in registers.
__device__ __forceinline__ u64 zs_regs(u64 w00, u64 w01, u64 w02,
                                       u64 w10, u64 w11, u64 w12,
                                       u64 w20, u64 w21, u64 w22, bool first) {
  const u64 P2 = w01;                          // N
  const u64 P3 = (w01 >> 1) | (w02 << 63);     // NE
  const u64 P4 = (w11 >> 1) | (w12 << 63);     // E
  const u64 P5 = (w21 >> 1) | (w22 << 63);     // SE
  const u64 P6 = w21;                          // S
  const u64 P7 = (w21 << 1) | (w20 >> 63);     // SW
  const u64 P8 = (w11 << 1) | (w10 >> 63);     // W
  const u64 P9 = (w01 << 1) | (w00 >> 63);     // NW

  u64 s1, c1, s2, c2, s3, c3, u0, u1, v1, v2;
  fa(P2, P3, P4, s1, c1);
  fa(P5, P6, P7, s2, c2);
  fa(P8, P9, 0ull, s3, c3);
  fa(s1, s2, s3, u0, u1);
  fa(c1, c2, c3, v1, v2);
  u64 b1 = u1 ^ v1, k2 = u1 & v1;
  u64 b2 = v2 ^ k2, b3 = v2 & k2;
  u64 condB = (b1 | b2 | b3) & ~(b3 | (b2 & b1 & u0));   // 2<=B<=6

  u64 t0 = ~P2 & P3, t1 = ~P3 & P4, t2 = ~P4 & P5, t3 = ~P5 & P6;
  u64 t4 = ~P6 & P7, t5 = ~P7 & P8, t6 = ~P8 & P9, t7 = ~P9 & P2;
  fa(t0, t1, t2, s1, c1);
  fa(t3, t4, t5, s2, c2);
  fa(t6, t7, 0ull, s3, c3);
  fa(s1, s2, s3, u0, u1);
  fa(c1, c2, c3, v1, v2);
  u64 a1 = u1 ^ v1, j2 = u1 & v1;
  u64 a2 = v2 ^ j2, a3 = v2 & j2;
  u64 condA = u0 & ~(a1 | a2 | a3);                      // A == 1

  u64 cc = first ? ((~(P2 & P4 & P6)) & (~(P4 & P6 & P8)))
                 : ((~(P2 & P4 & P8)) & (~(P2 & P6 & P8)));
  return w11 & ~(condB & condA & cc);
}

// Test 3 bits (padded word indices q..q+2) of the padded change mask U.
__device__ __forceinline__ bool dirty3(const u64* U, int q) {
  const int pb = q + 64;
  const int w = pb >> 6, sh = pb & 63;
  u64 v = U[w] >> sh;
  if (sh > 61) v |= U[w + 1] << (64 - sh);
  return (v & 7ull) != 0;
}

// One pruned subiteration over a z-slice: group(64-word) pre-test, then exact
// word-level dirty3 test. Clean words are fully skipped (dst holds the value
// from two passes ago, which is provably still correct).
template<bool FIRST>
__device__ __forceinline__ void subpassZ(const u64* __restrict__ src, u64* __restrict__ dst,
                                         u64* rawW, const u64* rawPrev,
                                         u64* Uw, const u64* Ur,
                                         u32* gmW, const u32* gmR,
                                         int* chgflag, int tid) {
  int anych = 0;
  for (int base = 0; base < NPZ; base += 1024) {
    const int idx = base + tid;
    int changed = 0;
    const bool valid = idx < NPZ;
    if (valid) {
      const int mw = 1 + (idx >> 6);
      if (gmR[mw - 1] | gmR[mw] | gmR[mw + 1]) {         // group-level pre-test
        const bool dirty = dirty3(Ur, idx - PADW - 1)
                         | dirty3(Ur, idx - 1)
                         | dirty3(Ur, idx + PADW - 1);
        if (dirty) {
          const u64 old = src[idx];
          u64 nw = 0;
          if (old) {
            nw = zs_regs(src[idx - PADW - 1], src[idx - PADW], src[idx - PADW + 1],
                         src[idx - 1], old, src[idx + 1],
                         src[idx + PADW - 1], src[idx + PADW], src[idx + PADW + 1], FIRST);
            changed = (nw != old);
          }
          dst[idx] = nw;
          anych |= changed;
        }
      }
    }
    const u64 bal = __ballot(changed != 0);
    if ((tid & 63) == 0 && valid) {
      const int mw = 1 + (idx >> 6);
      rawW[mw] = bal;
      const u64 uw = bal | rawPrev[mw];
      Uw[mw] = uw;
      gmW[mw] = (uw != 0ull) ? 1u : 0u;
    }
  }
  if (anych) *chgflag = 1;
}

// One dense xy subpass: 256 threads over a 50x8 padded slice in LDS.
// Pads have old==0 -> guarded; real words have idx in [9, 390].
template<bool FIRST>
__device__ __forceinline__ void xy_pass(const u64* __restrict__ S, u64* __restrict__ Dd,
                                        int lt, int* chg) {
  int anych = 0;
  for (int idx = lt; idx < NXY; idx += 256) {
    const u64 old = S[idx];
    u64 nw = 0;
    if (old) {
      nw = zs_regs(S[idx - 9], S[idx - 8], S[idx - 7],
                   S[idx - 1], old, S[idx + 1],
                   S[idx + 7], S[idx + 8], S[idx + 9], FIRST);
      anych |= (nw != old);
    }
    Dd[idx] = nw;
  }
  if (anych) *chg = 1;
}

// 240 blocks: b<48 -> one z-slice (pruned barrier loop);
//             b>=48 -> four xy slices, 256 threads each, shared barriers.
__global__ __launch_bounds__(1024) void thin_all(const u64* __restrict__ maskP,
                                                 u64* __restrict__ skelZY,
                                                 u64* __restrict__ skelX) {
  __shared__ u64 smem[2 * NPZ + 5 * MPAD2];   // 51.5 KB, covers both paths
  __shared__ int s_chg[2];
  __shared__ int s_xychg[2][4];
  const int b = blockIdx.x;
  const int tid = threadIdx.x;

  if (b < D) {
    // ---------------- z-slice path ----------------
    u64* A = smem;
    u64* B = A + NPZ;
    u64* raw0 = B + NPZ;
    u64* raw1 = raw0 + MPAD2;
    u64* Um0 = raw1 + MPAD2;
    u64* Um1 = Um0 + MPAD2;
    u32* gm0 = (u32*)(Um1 + MPAD2);
    u32* gm1 = gm0 + MPAD2;

    for (int idx = tid; idx < NPZ; idx += 1024) {
      const int rp = idx >> 3, cp = idx & 7;
      u64 v = 0;
      if (rp >= 1 && rp <= H && cp >= 1 && cp <= WPR)
        v = maskP[(b * H + (rp - 1)) * WPR + (cp - 1)];
      A[idx] = v;
      B[idx] = 0;
    }
    for (int t = tid; t < 4 * MPAD2; t += 1024) {
      const int arr = t / MPAD2, j = t - arr * MPAD2;
      const u64 v = ((arr & 1) && j >= 1 && j <= MWZ) ? ~0ull : 0ull;
      if (arr == 0) raw0[j] = v;
      else if (arr == 1) raw1[j] = v;
      else if (arr == 2) Um0[j] = v;
      else Um1[j] = v;
    }
    for (int t = tid; t < 2 * MPAD2; t += 1024) {
      const int arr = t / MPAD2, j = t - arr * MPAD2;
      const u32 v = (arr == 1 && j >= 1 && j <= MWZ) ? 1u : 0u;
      if (arr == 0) gm0[j] = v; else gm1[j] = v;
    }
    if (tid < 2) s_chg[tid] = 0;
    __syncthreads();

    int k = 0;
    while (true) {
      subpassZ<true >(A, B, raw0, raw1, Um0, Um1, gm0, gm1, &s_chg[k], tid);
      __syncthreads();
      if (tid == 0) s_chg[k ^ 1] = 0;
      subpassZ<false>(B, A, raw1, raw0, Um1, Um0, gm1, gm0, &s_chg[k], tid);
      __syncthreads();
      if (s_chg[k] == 0) break;
      k ^= 1;
    }

    for (int idx = tid; idx < NPZ; idx += 1024) {
      const int rp = idx >> 3, cp = idx & 7;
      if (rp < 1 || rp > H || cp < 1 || cp > WPR) continue;
      const u64 w = A[idx];
      if (!w) continue;
      atomicOr(&skelZY[(b * H + (rp - 1)) * WPR + (cp - 1)], w);
    }
  } else {
    // ---------------- xy path: 4 slices/block, 256 threads each ----------
    const int g = tid >> 8;            // subgroup 0..3
    const int lt = tid & 255;          // thread within subgroup
    const int s = (b - D) * 4 + g;     // slice id: 0..383 x-slices, 384..767 y
    u64* A = smem + g * (2 * NXY);
    u64* B = A + NXY;

    if (s < W) {
      // x-slice: rows z, cols y; bit-gather from maskP (L2-reuse across slices)
      const int lane = tid & 63;
      const int wv = (lt >> 6);        // wave within subgroup 0..3
      const int xw = s >> 6, xb = s & 63;
      for (int w = wv; w < NXY; w += 4) {
        const int rp = w >> 3, cp = w & 7;
        u64 val = 0;
        if (rp >= 1 && rp <= D && cp >= 1 && cp <= WPR) {
          const int c = (cp - 1) * 64 + lane;   // c = y
          u64 bit = (maskP[((rp - 1) * H + c) * WPR + xw] >> xb) & 1ull;
          val = __ballot(bit != 0);
        }
        if (lane == 0) { A[w] = val; B[w] = 0; }
      }
    } else {
      const int yy = s - W;
      for (int idx = lt; idx < NXY; idx += 256) {
        const int rp = idx >> 3, cp = idx & 7;
        u64 v = 0;
        if (rp >= 1 && rp <= D && cp >= 1 && cp <= WPR)
          v = maskP[((rp - 1) * H + yy) * WPR + (cp - 1)];
        A[idx] = v;
        B[idx] = 0;
      }
    }
    if (lt == 0) { s_xychg[0][g] = 0; s_xychg[1][g] = 0; }
    __syncthreads();

    int k = 0;
    bool act = true;
    while (true) {
      if (act) xy_pass<true >(A, B, lt, &s_xychg[k][g]);
      __syncthreads();
      if (lt == 0) s_xychg[k ^ 1][g] = 0;
      if (act) xy_pass<false>(B, A, lt, &s_xychg[k][g]);
      __syncthreads();
      const int c0 = s_xychg[k][0] | s_xychg[k][1] | s_xychg[k][2] | s_xychg[k][3];
      if (c0 == 0) break;
      act = (s_xychg[k][g] != 0);
      k ^= 1;
    }

    for (int idx = lt; idx < NXY; idx += 256) {
      const int rp = idx >> 3, cp = idx & 7;
      if (rp < 1 || rp > D || cp < 1 || cp > WPR) continue;
      const u64 w = A[idx];
      if (!w) continue;                          // targets zero-initialized
      if (s < W) skelX[((rp - 1) * W + s) * WPR + (cp - 1)] = w;   // exclusive
      else       atomicOr(&skelZY[((rp - 1) * H + (s - W)) * WPR + (cp - 1)], w);
    }
  }
}

// Pack mask bits (v==1.0f) along x; zero the skeleton accumulators.
__global__ void init_pack(const float* __restrict__ in, u64* __restrict__ maskP,
                          u64* __restrict__ skelZY, u64* __restrict__ skelX) {
  const int lane = threadIdx.x & 63;
  const int gwave = (blockIdx.x * blockDim.x + threadIdx.x) >> 6;
  const int nwaves = (gridDim.x * blockDim.x) >> 6;
  for (int widx = gwave; widx < NWVOL; widx += nwaves) {
    float v = in[(size_t)widx * 64 + lane];
    u64 w = __ballot(v == 1.0f);
    if (lane == 0) {
      maskP[widx] = w;
      skelZY[widx] = 0;
      skelX[widx] = 0;
    }
  }
}

// Transpose skelX ([z][x][yw], packed y) into packed-x layout, OR into skelZY.
// One wave per 64x64 bit tile: z fixed, x = xw*64+lane, y = yw*64+j.
__global__ void transpose_or(const u64* __restrict__ skelX,
                             u64* __restrict__ skelZY) {
  const int gw = (blockIdx.x * blockDim.x + threadIdx.x) >> 6;   // tile id
  const int lane = threadIdx.x & 63;
  const int z = gw / 36, rem = gw - z * 36;
  const int yw = rem / 6, xw = rem - yw * 6;
  const int x = xw * 64 + lane;
  const u64 wx = skelX[(z * W + x) * WPR + yw];   // bits indexed by y
  u64 mine = 0;
  #pragma unroll 8
  for (int j = 0; j < 64; ++j) {
    u64 wj = __ballot((wx >> j) & 1ull);          // bit l = pixel(y=yw*64+j, x=xw*64+l)
    if (lane == j) mine = wj;
  }
  const int y = yw * 64 + lane;
  if (mine) skelZY[(z * H + y) * WPR + xw] |= mine;   // exclusive owner per word
}

// 6-connected dilation per word (computed once into LDS) + mask + coalesced
// float4 expansion. One block = 64 words = 4096 voxels.
__global__ __launch_bounds__(256) void dilate_expand(const u64* __restrict__ maskP,
                                                     const u64* __restrict__ skelZY,
                                                     float* __restrict__ out) {
  __shared__ u64 rw[64];
  const int tid = threadIdx.x;
  const int wbase = blockIdx.x * 64;
  if (tid < 64) {
    const int wi = wbase + tid;
    const int wc = wi % WPR;
    const int row = wi / WPR;        // row = z*H + y
    const int y = row % H;
    const int z = row / H;
    const u64 S = skelZY[wi];
    const u64 L = (wc > 0) ? skelZY[wi - 1] : 0ull;
    const u64 Rw = (wc < WPR - 1) ? skelZY[wi + 1] : 0ull;
    u64 d = S | (S << 1) | (L >> 63) | (S >> 1) | (Rw << 63);
    if (y > 0)     d |= skelZY[wi - WPR];
    if (y < H - 1) d |= skelZY[wi + WPR];
    if (z > 0)     d |= skelZY[wi - H * WPR];
    if (z < D - 1) d |= skelZY[wi + H * WPR];
    rw[tid] = d & maskP[wi];
  }
  __syncthreads();
  float4* o4 = reinterpret_cast<float4*>(out + (size_t)wbase * 64);
  #pragma unroll
  for (int k = 0; k < 4; ++k) {
    const int f = tid + 256 * k;
    const u64 bits = rw[f >> 4] >> ((f & 15) * 4);
    float4 o;
    o.x = (float)(bits & 1ull);
    o.y = (float)((bits >> 1) & 1ull);
    o.z = (float)((bits >> 2) & 1ull);
    o.w = (float)((bits >> 3) & 1ull);
    o4[f] = o;
  }
}

extern "C" void kernel_launch(void* const* d_in, const int* in_sizes, int n_in,
                              void* d_out, int out_size, void* d_ws, size_t ws_size,
                              hipStream_t stream) {
  const float* in = (const float*)d_in[0];
  float* out = (float*)d_out;
  u64* wsw = (u64*)d_ws;                 // need 3 * 110592 * 8 B = 2.65 MB
  u64* maskP = wsw;
  u64* skelZY = wsw + NWVOL;
  u64* skelX = wsw + 2 * NWVOL;

  init_pack<<<1728, 256, 0, stream>>>(in, maskP, skelZY, skelX);
  thin_all<<<D + 768 / 4, 1024, 0, stream>>>(maskP, skelZY, skelX);
  transpose_or<<<(NWVOL + 255) / 256, 256, 0, stream>>>(skelX, skelZY);
  dilate_expand<<<NWVOL / 64, 256, 0, stream>>>(maskP, skelZY, out);
}